// Round 1
// baseline (384.254 us; speedup 1.0000x reference)
//
#include <hip/hip_runtime.h>

#define BN_EPS 1e-5f

// ---------------- CSR build (dst-sorted edge list) ----------------
__global__ void hist_kernel(const int* __restrict__ dst, int* __restrict__ deg, int e) {
    int i = blockIdx.x * blockDim.x + threadIdx.x;
    if (i < e) atomicAdd(&deg[dst[i]], 1);
}

__global__ void scan_excl(const int* __restrict__ deg, int* __restrict__ rowstart, int n) {
    __shared__ int tmp[1024];
    __shared__ int carry_s;
    int tid = threadIdx.x;
    if (tid == 0) { carry_s = 0; rowstart[0] = 0; }
    __syncthreads();
    for (int base = 0; base < n; base += 1024) {
        int i = base + tid;
        int v = (i < n) ? deg[i] : 0;
        tmp[tid] = v;
        __syncthreads();
        for (int off = 1; off < 1024; off <<= 1) {
            int t = (tid >= off) ? tmp[tid - off] : 0;
            __syncthreads();
            tmp[tid] += t;
            __syncthreads();
        }
        if (i < n) rowstart[i + 1] = carry_s + tmp[tid];
        __syncthreads();
        if (tid == 0) carry_s += tmp[1023];
        __syncthreads();
    }
}

__global__ void scatter_kernel(const int* __restrict__ dst, const int* __restrict__ rowstart,
                               int* __restrict__ cursor, int* __restrict__ perm, int e) {
    int i = blockIdx.x * blockDim.x + threadIdx.x;
    if (i < e) {
        int d = dst[i];
        int pos = atomicAdd(&cursor[d], 1);
        perm[rowstart[d] + pos] = i;
    }
}

// ---------------- weight packing: Wcat[K][1024] = [Wq|Wk|Wv|Ws], bcat[1024] ----------------
__global__ void pack_w(const float* __restrict__ Wq, const float* __restrict__ Wk,
                       const float* __restrict__ Wv, const float* __restrict__ Ws,
                       const float* __restrict__ bq, const float* __restrict__ bk,
                       const float* __restrict__ bv, const float* __restrict__ bs,
                       float* __restrict__ Wcat, float* __restrict__ bcat, int K) {
    int idx = blockIdx.x * blockDim.x + threadIdx.x;
    int total = K * 1024;
    if (idx < total) {
        int k = idx >> 10, c = idx & 1023;
        const float* W = (c < 256) ? Wq : (c < 512) ? Wk : (c < 768) ? Wv : Ws;
        Wcat[idx] = W[k * 256 + (c & 255)];
    }
    if (idx < 1024) {
        const float* b = (idx < 256) ? bq : (idx < 512) ? bk : (idx < 768) ? bv : bs;
        bcat[idx] = b[idx & 255];
    }
}

// ---------------- fused QKVS GEMM: C[M][1024] = A[M][K] * B[K][1024] + bias ----------------
// 64x64 tile, 256 threads, 4x4 micro-tile per thread, fp32
__global__ __launch_bounds__(256) void gemm_qkvs(const float* __restrict__ A,
                                                 const float* __restrict__ B,
                                                 const float* __restrict__ bias,
                                                 float* __restrict__ C,
                                                 int M, int K) {
    __shared__ float As[16][64];   // [k][row]
    __shared__ float Bs[16][64];   // [k][col]
    int tx = threadIdx.x & 15;     // col group
    int ty = threadIdx.x >> 4;     // row group
    int rowBase = blockIdx.x * 64;
    int colBase = blockIdx.y * 64;

    float4 acc[4];
    #pragma unroll
    for (int i = 0; i < 4; ++i) acc[i] = make_float4(0.f, 0.f, 0.f, 0.f);

    int lrow = threadIdx.x >> 2;           // 0..63, A-tile row
    int lcg  = (threadIdx.x & 3) * 4;      // A-tile k-group
    int brow = threadIdx.x >> 4;           // 0..15, B-tile k row
    int bcg  = (threadIdx.x & 15) * 4;     // B-tile col group

    for (int k0 = 0; k0 < K; k0 += 16) {
        int ar = rowBase + lrow;
        float4 av = (ar < M) ? *(const float4*)&A[(size_t)ar * K + k0 + lcg]
                             : make_float4(0.f, 0.f, 0.f, 0.f);
        As[lcg + 0][lrow] = av.x;
        As[lcg + 1][lrow] = av.y;
        As[lcg + 2][lrow] = av.z;
        As[lcg + 3][lrow] = av.w;
        *(float4*)&Bs[brow][bcg] = *(const float4*)&B[(size_t)(k0 + brow) * 1024 + colBase + bcg];
        __syncthreads();
        #pragma unroll
        for (int k = 0; k < 16; ++k) {
            float4 b4 = *(const float4*)&Bs[k][tx * 4];
            float4 a4 = *(const float4*)&As[k][ty * 4];
            acc[0].x += a4.x * b4.x; acc[0].y += a4.x * b4.y; acc[0].z += a4.x * b4.z; acc[0].w += a4.x * b4.w;
            acc[1].x += a4.y * b4.x; acc[1].y += a4.y * b4.y; acc[1].z += a4.y * b4.z; acc[1].w += a4.y * b4.w;
            acc[2].x += a4.z * b4.x; acc[2].y += a4.z * b4.y; acc[2].z += a4.z * b4.z; acc[2].w += a4.z * b4.w;
            acc[3].x += a4.w * b4.x; acc[3].y += a4.w * b4.y; acc[3].z += a4.w * b4.z; acc[3].w += a4.w * b4.w;
        }
        __syncthreads();
    }

    float4 bb = *(const float4*)&bias[colBase + tx * 4];
    #pragma unroll
    for (int i = 0; i < 4; ++i) {
        int r = rowBase + ty * 4 + i;
        if (r < M) {
            float4 o;
            o.x = acc[i].x + bb.x; o.y = acc[i].y + bb.y;
            o.z = acc[i].z + bb.z; o.w = acc[i].w + bb.w;
            *(float4*)&C[(size_t)r * 1024 + colBase + tx * 4] = o;
        }
    }
}

// ---------------- per-node attention: one wave per destination node ----------------
// QKVS layout per node: [0:256)=Q, [256:512)=K, [512:768)=V, [768:1024)=Skip
__global__ __launch_bounds__(256) void attn_kernel(const float* __restrict__ QKVS,
                                                   const int* __restrict__ src,
                                                   const float* __restrict__ ea,
                                                   const float* __restrict__ We,
                                                   const int* __restrict__ rowstart,
                                                   const int* __restrict__ perm,
                                                   float* __restrict__ alpha_ws,
                                                   float* __restrict__ out, int n) {
    __shared__ float We_lds[256];
    We_lds[threadIdx.x] = We[threadIdx.x];
    __syncthreads();
    int wave = threadIdx.x >> 6;
    int lane = threadIdx.x & 63;
    int node = blockIdx.x * 4 + wave;
    if (node >= n) return;
    int col = lane * 4;                    // lanes 0..31 = head 0, 32..63 = head 1
    int h = lane >> 5;
    float4 we4 = *(const float4*)&We_lds[col];
    float4 q4  = *(const float4*)&QKVS[(size_t)node * 1024 + col];
    int beg = rowstart[node], end = rowstart[node + 1];
    const float scale = 0.08838834764831845f;   // 1/sqrt(128)

    float m = -INFINITY;
    for (int i = beg; i < end; ++i) {
        int eid = perm[i];
        int s = src[eid];
        float a = ea[eid];
        float4 k4 = *(const float4*)&QKVS[(size_t)s * 1024 + 256 + col];
        float p = q4.x * (k4.x + a * we4.x) + q4.y * (k4.y + a * we4.y)
                + q4.z * (k4.z + a * we4.z) + q4.w * (k4.w + a * we4.w);
        #pragma unroll
        for (int off = 16; off >= 1; off >>= 1) p += __shfl_xor(p, off, 64);
        float alpha = p * scale;
        m = fmaxf(m, alpha);
        if ((lane & 31) == 0) alpha_ws[(size_t)eid * 2 + h] = alpha;
    }

    float ssum = 0.f;
    float4 acc = make_float4(0.f, 0.f, 0.f, 0.f);
    for (int i = beg; i < end; ++i) {
        int eid = perm[i];
        int s = src[eid];
        float a = ea[eid];
        float alpha = alpha_ws[(size_t)eid * 2 + h];
        float w = __expf(alpha - m);
        ssum += w;
        float4 v4 = *(const float4*)&QKVS[(size_t)s * 1024 + 512 + col];
        acc.x += w * (v4.x + a * we4.x);
        acc.y += w * (v4.y + a * we4.y);
        acc.z += w * (v4.z + a * we4.z);
        acc.w += w * (v4.w + a * we4.w);
    }
    float inv = 1.0f / (ssum + 1e-16f);
    float4 sk = *(const float4*)&QKVS[(size_t)node * 1024 + 768 + col];
    float4 o;
    o.x = acc.x * inv + sk.x; o.y = acc.y * inv + sk.y;
    o.z = acc.z * inv + sk.z; o.w = acc.w * inv + sk.w;
    *(float4*)&out[(size_t)node * 256 + col] = o;
}

// ---------------- BatchNorm ----------------
__global__ void bn_stats(const float* __restrict__ x, float* __restrict__ sums, int n) {
    int c = threadIdx.x;  // 256
    float s = 0.f, s2 = 0.f;
    for (int r = blockIdx.x; r < n; r += gridDim.x) {
        float v = x[(size_t)r * 256 + c];
        s += v; s2 += v * v;
    }
    atomicAdd(&sums[c], s);
    atomicAdd(&sums[256 + c], s2);
}

__global__ void bn_apply(const float* __restrict__ x, const float* __restrict__ sums,
                         const float* __restrict__ g, const float* __restrict__ b,
                         float* __restrict__ y, int n) {
    int idx = blockIdx.x * blockDim.x + threadIdx.x;
    if (idx >= n * 256) return;
    int c = idx & 255;
    float invn = 1.0f / (float)n;
    float mu = sums[c] * invn;
    float var = sums[256 + c] * invn - mu * mu;
    float v = (x[idx] - mu) * rsqrtf(var + BN_EPS) * g[c] + b[c];
    y[idx] = fmaxf(v, 0.f);
}

extern "C" void kernel_launch(void* const* d_in, const int* in_sizes, int n_in,
                              void* d_out, int out_size, void* d_ws, size_t ws_size,
                              hipStream_t stream) {
    const float* x         = (const float*)d_in[0];
    const int*   edge_idx  = (const int*)d_in[1];
    const float* edge_attr = (const float*)d_in[2];
    const float* Wq1 = (const float*)d_in[3];  const float* bq1 = (const float*)d_in[4];
    const float* Wk1 = (const float*)d_in[5];  const float* bk1 = (const float*)d_in[6];
    const float* Wv1 = (const float*)d_in[7];  const float* bv1 = (const float*)d_in[8];
    const float* We1 = (const float*)d_in[9];
    const float* Ws1 = (const float*)d_in[10]; const float* bs1 = (const float*)d_in[11];
    const float* g1  = (const float*)d_in[12]; const float* b1  = (const float*)d_in[13];
    const float* Wq2 = (const float*)d_in[14]; const float* bq2 = (const float*)d_in[15];
    const float* Wk2 = (const float*)d_in[16]; const float* bk2 = (const float*)d_in[17];
    const float* Wv2 = (const float*)d_in[18]; const float* bv2 = (const float*)d_in[19];
    const float* We2 = (const float*)d_in[20];
    const float* Ws2 = (const float*)d_in[21]; const float* bs2 = (const float*)d_in[22];
    const float* g2  = (const float*)d_in[23]; const float* b2  = (const float*)d_in[24];

    const int N = in_sizes[0] / 128;   // 10000
    const int E = in_sizes[1] / 2;     // 160000
    const int* src = edge_idx;
    const int* dst = edge_idx + E;

    // workspace carve-out
    char* ws = (char*)d_ws;
    size_t off = 0;
    auto alloc = [&](size_t bytes) -> void* {
        void* p = ws + off;
        off += (bytes + 255) & ~(size_t)255;
        return p;
    };
    float* qkvs     = (float*)alloc((size_t)N * 1024 * 4);
    float* attn_out = (float*)alloc((size_t)N * 256 * 4);
    float* h1       = (float*)alloc((size_t)N * 256 * 4);
    float* Wcat     = (float*)alloc((size_t)256 * 1024 * 4);
    float* bcat     = (float*)alloc(1024 * 4);
    int*   deg      = (int*)alloc((size_t)N * 4);
    int*   rowstart = (int*)alloc((size_t)(N + 1) * 4);
    int*   cursor   = (int*)alloc((size_t)N * 4);
    int*   perm     = (int*)alloc((size_t)E * 4);
    float* alpha_ws = (float*)alloc((size_t)E * 2 * 4);
    float* bn_sums  = (float*)alloc(512 * 4);

    // ---- CSR build (shared by both layers) ----
    hipMemsetAsync(deg, 0, (size_t)N * 4, stream);
    hipMemsetAsync(cursor, 0, (size_t)N * 4, stream);
    hist_kernel<<<(E + 255) / 256, 256, 0, stream>>>(dst, deg, E);
    scan_excl<<<1, 1024, 0, stream>>>(deg, rowstart, N);
    scatter_kernel<<<(E + 255) / 256, 256, 0, stream>>>(dst, rowstart, cursor, perm, E);

    dim3 gemm_grid((N + 63) / 64, 16);
    int attn_blocks = (N + 3) / 4;

    // ---- layer 1 (K = 128) ----
    pack_w<<<(128 * 1024 + 255) / 256, 256, 0, stream>>>(Wq1, Wk1, Wv1, Ws1, bq1, bk1, bv1, bs1,
                                                         Wcat, bcat, 128);
    gemm_qkvs<<<gemm_grid, 256, 0, stream>>>(x, Wcat, bcat, qkvs, N, 128);
    attn_kernel<<<attn_blocks, 256, 0, stream>>>(qkvs, src, edge_attr, We1, rowstart, perm,
                                                 alpha_ws, attn_out, N);
    hipMemsetAsync(bn_sums, 0, 512 * 4, stream);
    bn_stats<<<256, 256, 0, stream>>>(attn_out, bn_sums, N);
    bn_apply<<<(N * 256 + 255) / 256, 256, 0, stream>>>(attn_out, bn_sums, g1, b1, h1, N);

    // ---- layer 2 (K = 256) ----
    pack_w<<<(256 * 1024 + 255) / 256, 256, 0, stream>>>(Wq2, Wk2, Wv2, Ws2, bq2, bk2, bv2, bs2,
                                                         Wcat, bcat, 256);
    gemm_qkvs<<<gemm_grid, 256, 0, stream>>>(h1, Wcat, bcat, qkvs, N, 256);
    attn_kernel<<<attn_blocks, 256, 0, stream>>>(qkvs, src, edge_attr, We2, rowstart, perm,
                                                 alpha_ws, attn_out, N);
    hipMemsetAsync(bn_sums, 0, 512 * 4, stream);
    bn_stats<<<256, 256, 0, stream>>>(attn_out, bn_sums, N);
    bn_apply<<<(N * 256 + 255) / 256, 256, 0, stream>>>(attn_out, bn_sums, g2, b2, (float*)d_out, N);
}

// Round 2
// 254.648 us; speedup vs baseline: 1.5090x; 1.5090x over previous
//
#include <hip/hip_runtime.h>

#define BN_EPS 1e-5f

using f32x4 = __attribute__((ext_vector_type(4))) float;
using s16x8 = __attribute__((ext_vector_type(8))) short;
using u32x4 = __attribute__((ext_vector_type(4))) unsigned int;

__device__ __forceinline__ unsigned short f2bf(float f) {
    unsigned u = __float_as_uint(f);
    u += 0x7fffu + ((u >> 16) & 1u);   // round-to-nearest-even
    return (unsigned short)(u >> 16);
}

// ---------------- CSR build (dst-sorted edge list) ----------------
__global__ void hist_kernel(const int* __restrict__ dst, int* __restrict__ deg, int e) {
    int i = blockIdx.x * blockDim.x + threadIdx.x;
    if (i < e) atomicAdd(&deg[dst[i]], 1);
}

// single block, 1024 threads: each thread scans a contiguous chunk; wave-scan of chunk sums
__global__ void scan_excl(const int* __restrict__ deg, int* __restrict__ rowstart, int n) {
    __shared__ int wsum[16];
    int tid = threadIdx.x;
    int per = (n + 1023) >> 10;
    int b0 = tid * per;
    int s = 0;
    for (int j = 0; j < per; ++j) {
        int i = b0 + j;
        if (i < n) s += deg[i];
    }
    int lane = tid & 63, w = tid >> 6;
    int v = s;
    #pragma unroll
    for (int off = 1; off < 64; off <<= 1) {
        int t = __shfl_up(v, off, 64);
        if (lane >= off) v += t;
    }
    if (lane == 63) wsum[w] = v;
    __syncthreads();
    if (w == 0) {
        int t = (lane < 16) ? wsum[lane] : 0;
        #pragma unroll
        for (int off = 1; off < 16; off <<= 1) {
            int u = __shfl_up(t, off, 64);
            if (lane >= off) t += u;
        }
        if (lane < 16) wsum[lane] = t;
    }
    __syncthreads();
    int base = (w > 0 ? wsum[w - 1] : 0) + v - s;   // exclusive prefix of this chunk
    for (int j = 0; j < per; ++j) {
        int i = b0 + j;
        if (i < n) { rowstart[i] = base; base += deg[i]; }
    }
    if (tid == 0) rowstart[n] = wsum[15];
}

__global__ void scatter_kernel(const int* __restrict__ dst, const int* __restrict__ rowstart,
                               int* __restrict__ cursor, int* __restrict__ perm, int e) {
    int i = blockIdx.x * blockDim.x + threadIdx.x;
    if (i < e) {
        int d = dst[i];
        int pos = atomicAdd(&cursor[d], 1);
        perm[rowstart[d] + pos] = i;
    }
}

// ---------------- pack weights: Wt[c][K] = bf16(W[k][c&255]) for panel c/256, bcat fp32 ----------------
__global__ void pack_w(const float* __restrict__ Wq, const float* __restrict__ Wk,
                       const float* __restrict__ Wv, const float* __restrict__ Ws,
                       const float* __restrict__ bq, const float* __restrict__ bk,
                       const float* __restrict__ bv, const float* __restrict__ bs,
                       unsigned short* __restrict__ Wt, float* __restrict__ bcat, int K) {
    int idx = blockIdx.x * blockDim.x + threadIdx.x;
    if (idx < 1024 * K) {
        int c = idx / K, k = idx - c * K;
        const float* W = (c < 256) ? Wq : (c < 512) ? Wk : (c < 768) ? Wv : Ws;
        Wt[idx] = f2bf(W[k * 256 + (c & 255)]);
    }
    if (idx < 1024) {
        const float* b = (idx < 256) ? bq : (idx < 512) ? bk : (idx < 768) ? bv : bs;
        bcat[idx] = b[idx & 255];
    }
}

__global__ void to_bf16(const float* __restrict__ in, unsigned short* __restrict__ out, int n4) {
    int i = blockIdx.x * blockDim.x + threadIdx.x;
    if (i < n4) {
        float4 v = ((const float4*)in)[i];
        ushort4 o;
        o.x = f2bf(v.x); o.y = f2bf(v.y); o.z = f2bf(v.z); o.w = f2bf(v.w);
        ((ushort4*)out)[i] = o;
    }
}

// ---------------- bf16 MFMA GEMM: C[M][1024] = A[M][K] x Bt[1024][K]^T + bias ----------------
// 128x128 tile, BK=64, 4 waves (2x2), each wave 64x64 = 4x4 fragments of 16x16x32
__global__ __launch_bounds__(256) void gemm_mfma(const unsigned short* __restrict__ A,
                                                 const unsigned short* __restrict__ Bt,
                                                 const float* __restrict__ bias,
                                                 float* __restrict__ C, int M, int K) {
    __shared__ unsigned short As[128][72];   // 64 + 8 pad (16B) -> conflict-free b128
    __shared__ unsigned short Bs[128][72];
    const int tid = threadIdx.x;
    const int lane = tid & 63;
    const int wave = tid >> 6;
    const int wr = (wave >> 1) * 64;
    const int wc = (wave & 1) * 64;
    const int g = lane >> 4;        // k-group
    const int r16 = lane & 15;
    const int rowBase = blockIdx.x * 128;
    const int colBase = blockIdx.y * 128;

    const int srow = tid >> 1;           // staging row/col 0..127
    const int skh = (tid & 1) * 32;      // k-half

    f32x4 acc[4][4];
    #pragma unroll
    for (int i = 0; i < 4; ++i)
        #pragma unroll
        for (int j = 0; j < 4; ++j)
            acc[i][j] = (f32x4){0.f, 0.f, 0.f, 0.f};

    for (int k0 = 0; k0 < K; k0 += 64) {
        {
            int grow = rowBase + srow;
            bool ok = grow < M;
            const unsigned short* pa = &A[(size_t)(ok ? grow : 0) * K + k0 + skh];
            #pragma unroll
            for (int i = 0; i < 4; ++i) {
                u32x4 v = ok ? *(const u32x4*)(pa + i * 8) : (u32x4){0u, 0u, 0u, 0u};
                *(u32x4*)&As[srow][skh + i * 8] = v;
            }
            const unsigned short* pb = &Bt[(size_t)(colBase + srow) * K + k0 + skh];
            #pragma unroll
            for (int i = 0; i < 4; ++i)
                *(u32x4*)&Bs[srow][skh + i * 8] = *(const u32x4*)(pb + i * 8);
        }
        __syncthreads();
        #pragma unroll
        for (int kk = 0; kk < 64; kk += 32) {
            s16x8 af[4], bf[4];
            #pragma unroll
            for (int i = 0; i < 4; ++i) af[i] = *(const s16x8*)&As[wr + i * 16 + r16][kk + g * 8];
            #pragma unroll
            for (int j = 0; j < 4; ++j) bf[j] = *(const s16x8*)&Bs[wc + j * 16 + r16][kk + g * 8];
            #pragma unroll
            for (int i = 0; i < 4; ++i)
                #pragma unroll
                for (int j = 0; j < 4; ++j)
                    acc[i][j] = __builtin_amdgcn_mfma_f32_16x16x32_bf16(af[i], bf[j], acc[i][j], 0, 0, 0);
        }
        __syncthreads();
    }

    #pragma unroll
    for (int j = 0; j < 4; ++j) {
        int gcol = colBase + wc + j * 16 + r16;
        float bb = bias[gcol];
        #pragma unroll
        for (int i = 0; i < 4; ++i) {
            #pragma unroll
            for (int r = 0; r < 4; ++r) {
                int grow = rowBase + wr + i * 16 + g * 4 + r;
                if (grow < M) C[(size_t)grow * 1024 + gcol] = acc[i][j][r] + bb;
            }
        }
    }
}

// ---------------- attention: one wave per dst node, single-pass online softmax ----------------
// quarter-wave per (edge-slot, head): lanes[5]=edge slot, [4]=head, [3:0]=channel group (8 ch)
// QKVS per node: [0:256)=Q, [256:512)=K, [512:768)=V, [768:1024)=Skip
__global__ __launch_bounds__(256) void attn_kernel(const float* __restrict__ QKVS,
                                                   const int* __restrict__ src,
                                                   const float* __restrict__ ea,
                                                   const float* __restrict__ We,
                                                   const int* __restrict__ rowstart,
                                                   const int* __restrict__ perm,
                                                   float* __restrict__ out, int n) {
    int wave = threadIdx.x >> 6, lane = threadIdx.x & 63;
    int node = blockIdx.x * 4 + wave;
    if (node >= n) return;
    int epar = lane >> 5;
    int h = (lane >> 4) & 1;
    int cl = (lane & 15) * 8;
    int hc = h * 128 + cl;

    float4 q0 = *(const float4*)&QKVS[(size_t)node * 1024 + hc];
    float4 q1 = *(const float4*)&QKVS[(size_t)node * 1024 + hc + 4];
    float4 we0 = *(const float4*)&We[hc];
    float4 we1 = *(const float4*)&We[hc + 4];
    int beg = rowstart[node], end = rowstart[node + 1];
    const float scale = 0.08838834764831845f;   // 1/sqrt(128)

    float m = -INFINITY, ssum = 0.f;
    float4 acc0 = {0.f, 0.f, 0.f, 0.f}, acc1 = {0.f, 0.f, 0.f, 0.f};

    for (int i0 = beg; i0 < end; i0 += 2) {
        int i = i0 + epar;
        bool valid = i < end;
        int eid = perm[valid ? i : beg];
        int s = src[eid];
        float a = ea[eid];
        const float* kp = &QKVS[(size_t)s * 1024 + 256 + hc];
        const float* vp = &QKVS[(size_t)s * 1024 + 512 + hc];
        float4 k0 = *(const float4*)kp, k1 = *(const float4*)(kp + 4);
        float4 v0 = *(const float4*)vp, v1 = *(const float4*)(vp + 4);
        float e0x = a * we0.x, e0y = a * we0.y, e0z = a * we0.z, e0w = a * we0.w;
        float e1x = a * we1.x, e1y = a * we1.y, e1z = a * we1.z, e1w = a * we1.w;
        float p = q0.x * (k0.x + e0x) + q0.y * (k0.y + e0y)
                + q0.z * (k0.z + e0z) + q0.w * (k0.w + e0w)
                + q1.x * (k1.x + e1x) + q1.y * (k1.y + e1y)
                + q1.z * (k1.z + e1z) + q1.w * (k1.w + e1w);
        p += __shfl_xor(p, 1, 64);
        p += __shfl_xor(p, 2, 64);
        p += __shfl_xor(p, 4, 64);
        p += __shfl_xor(p, 8, 64);
        float alpha = valid ? p * scale : -INFINITY;
        float mnew = fmaxf(m, alpha);
        float corr = __expf(fminf(m - mnew, 0.f));   // fmin(nan,0)=0 -> corr=1 when both -inf
        float w = valid ? __expf(alpha - mnew) : 0.f;
        ssum = ssum * corr + w;
        acc0.x = acc0.x * corr + w * (v0.x + e0x);
        acc0.y = acc0.y * corr + w * (v0.y + e0y);
        acc0.z = acc0.z * corr + w * (v0.z + e0z);
        acc0.w = acc0.w * corr + w * (v0.w + e0w);
        acc1.x = acc1.x * corr + w * (v1.x + e1x);
        acc1.y = acc1.y * corr + w * (v1.y + e1y);
        acc1.z = acc1.z * corr + w * (v1.z + e1z);
        acc1.w = acc1.w * corr + w * (v1.w + e1w);
        m = mnew;
    }

    // merge the two edge-slot partials (lane ^ 32)
    float m2 = __shfl_xor(m, 32, 64);
    float mm = fmaxf(m, m2);
    float cw = __expf(fminf(m - mm, 0.f));
    float sw = ssum * cw;
    sw += __shfl_xor(sw, 32, 64);
    float o[8];
    o[0] = acc0.x * cw; o[1] = acc0.y * cw; o[2] = acc0.z * cw; o[3] = acc0.w * cw;
    o[4] = acc1.x * cw; o[5] = acc1.y * cw; o[6] = acc1.z * cw; o[7] = acc1.w * cw;
    #pragma unroll
    for (int t = 0; t < 8; ++t) o[t] += __shfl_xor(o[t], 32, 64);

    if (epar == 0) {
        float inv = 1.0f / (sw + 1e-16f);
        float4 sk0 = *(const float4*)&QKVS[(size_t)node * 1024 + 768 + hc];
        float4 sk1 = *(const float4*)&QKVS[(size_t)node * 1024 + 768 + hc + 4];
        float4 r0, r1;
        r0.x = o[0] * inv + sk0.x; r0.y = o[1] * inv + sk0.y;
        r0.z = o[2] * inv + sk0.z; r0.w = o[3] * inv + sk0.w;
        r1.x = o[4] * inv + sk1.x; r1.y = o[5] * inv + sk1.y;
        r1.z = o[6] * inv + sk1.z; r1.w = o[7] * inv + sk1.w;
        *(float4*)&out[(size_t)node * 256 + hc] = r0;
        *(float4*)&out[(size_t)node * 256 + hc + 4] = r1;
    }
}

// ---------------- BatchNorm ----------------
__global__ void bn_stats(const float* __restrict__ x, float* __restrict__ sums, int n) {
    int c = threadIdx.x;  // 256
    float s = 0.f, s2 = 0.f;
    for (int r = blockIdx.x; r < n; r += gridDim.x) {
        float v = x[(size_t)r * 256 + c];
        s += v; s2 += v * v;
    }
    atomicAdd(&sums[c], s);
    atomicAdd(&sums[256 + c], s2);
}

__global__ void bn_apply_bf16(const float* __restrict__ x, const float* __restrict__ sums,
                              const float* __restrict__ g, const float* __restrict__ b,
                              unsigned short* __restrict__ y, int n) {
    int idx = blockIdx.x * blockDim.x + threadIdx.x;
    if (idx >= n * 256) return;
    int c = idx & 255;
    float invn = 1.0f / (float)n;
    float mu = sums[c] * invn;
    float var = sums[256 + c] * invn - mu * mu;
    float v = (x[idx] - mu) * rsqrtf(var + BN_EPS) * g[c] + b[c];
    y[idx] = f2bf(fmaxf(v, 0.f));
}

__global__ void bn_apply(const float* __restrict__ x, const float* __restrict__ sums,
                         const float* __restrict__ g, const float* __restrict__ b,
                         float* __restrict__ y, int n) {
    int idx = blockIdx.x * blockDim.x + threadIdx.x;
    if (idx >= n * 256) return;
    int c = idx & 255;
    float invn = 1.0f / (float)n;
    float mu = sums[c] * invn;
    float var = sums[256 + c] * invn - mu * mu;
    float v = (x[idx] - mu) * rsqrtf(var + BN_EPS) * g[c] + b[c];
    y[idx] = fmaxf(v, 0.f);
}

extern "C" void kernel_launch(void* const* d_in, const int* in_sizes, int n_in,
                              void* d_out, int out_size, void* d_ws, size_t ws_size,
                              hipStream_t stream) {
    const float* x         = (const float*)d_in[0];
    const int*   edge_idx  = (const int*)d_in[1];
    const float* edge_attr = (const float*)d_in[2];
    const float* Wq1 = (const float*)d_in[3];  const float* bq1 = (const float*)d_in[4];
    const float* Wk1 = (const float*)d_in[5];  const float* bk1 = (const float*)d_in[6];
    const float* Wv1 = (const float*)d_in[7];  const float* bv1 = (const float*)d_in[8];
    const float* We1 = (const float*)d_in[9];
    const float* Ws1 = (const float*)d_in[10]; const float* bs1 = (const float*)d_in[11];
    const float* g1  = (const float*)d_in[12]; const float* b1  = (const float*)d_in[13];
    const float* Wq2 = (const float*)d_in[14]; const float* bq2 = (const float*)d_in[15];
    const float* Wk2 = (const float*)d_in[16]; const float* bk2 = (const float*)d_in[17];
    const float* Wv2 = (const float*)d_in[18]; const float* bv2 = (const float*)d_in[19];
    const float* We2 = (const float*)d_in[20];
    const float* Ws2 = (const float*)d_in[21]; const float* bs2 = (const float*)d_in[22];
    const float* g2  = (const float*)d_in[23]; const float* b2  = (const float*)d_in[24];

    const int N = in_sizes[0] / 128;   // 10000
    const int E = in_sizes[1] / 2;     // 160000
    const int* src = edge_idx;
    const int* dst = edge_idx + E;

    char* ws = (char*)d_ws;
    size_t off = 0;
    auto alloc = [&](size_t bytes) -> void* {
        void* p = ws + off;
        off += (bytes + 255) & ~(size_t)255;
        return p;
    };
    float*          qkvs     = (float*)alloc((size_t)N * 1024 * 4);
    float*          attn_out = (float*)alloc((size_t)N * 256 * 4);
    unsigned short* h1b      = (unsigned short*)alloc((size_t)N * 256 * 2);
    unsigned short* xb       = (unsigned short*)alloc((size_t)N * 128 * 2);
    unsigned short* Wt       = (unsigned short*)alloc((size_t)1024 * 256 * 2);
    float*          bcat     = (float*)alloc(1024 * 4);
    int*            deg      = (int*)alloc((size_t)N * 4);
    int*            rowstart = (int*)alloc((size_t)(N + 1) * 4);
    int*            cursor   = (int*)alloc((size_t)N * 4);
    int*            perm     = (int*)alloc((size_t)E * 4);
    float*          bn_sums  = (float*)alloc(512 * 4);

    // ---- CSR build (shared by both layers) ----
    hipMemsetAsync(deg, 0, (size_t)N * 4, stream);
    hipMemsetAsync(cursor, 0, (size_t)N * 4, stream);
    hist_kernel<<<(E + 255) / 256, 256, 0, stream>>>(dst, deg, E);
    scan_excl<<<1, 1024, 0, stream>>>(deg, rowstart, N);
    scatter_kernel<<<(E + 255) / 256, 256, 0, stream>>>(dst, rowstart, cursor, perm, E);

    dim3 gemm_grid((N + 127) / 128, 8);
    int attn_blocks = (N + 3) / 4;

    // ---- layer 1 (K = 128) ----
    to_bf16<<<((N * 128 / 4) + 255) / 256, 256, 0, stream>>>(x, xb, N * 128 / 4);
    pack_w<<<(1024 * 128 + 255) / 256, 256, 0, stream>>>(Wq1, Wk1, Wv1, Ws1, bq1, bk1, bv1, bs1,
                                                         Wt, bcat, 128);
    gemm_mfma<<<gemm_grid, 256, 0, stream>>>(xb, Wt, bcat, qkvs, N, 128);
    attn_kernel<<<attn_blocks, 256, 0, stream>>>(qkvs, src, edge_attr, We1, rowstart, perm,
                                                 attn_out, N);
    hipMemsetAsync(bn_sums, 0, 512 * 4, stream);
    bn_stats<<<256, 256, 0, stream>>>(attn_out, bn_sums, N);
    bn_apply_bf16<<<(N * 256 + 255) / 256, 256, 0, stream>>>(attn_out, bn_sums, g1, b1, h1b, N);

    // ---- layer 2 (K = 256) ----
    pack_w<<<(1024 * 256 + 255) / 256, 256, 0, stream>>>(Wq2, Wk2, Wv2, Ws2, bq2, bk2, bv2, bs2,
                                                         Wt, bcat, 256);
    gemm_mfma<<<gemm_grid, 256, 0, stream>>>(h1b, Wt, bcat, qkvs, N, 256);
    attn_kernel<<<attn_blocks, 256, 0, stream>>>(qkvs, src, edge_attr, We2, rowstart, perm,
                                                 attn_out, N);
    hipMemsetAsync(bn_sums, 0, 512 * 4, stream);
    bn_stats<<<256, 256, 0, stream>>>(attn_out, bn_sums, N);
    bn_apply<<<(N * 256 + 255) / 256, 256, 0, stream>>>(attn_out, bn_sums, g2, b2, (float*)d_out, N);
}

// Round 3
// 208.217 us; speedup vs baseline: 1.8455x; 1.2230x over previous
//
#include <hip/hip_runtime.h>

#define BN_EPS 1e-5f

using f32x4 = __attribute__((ext_vector_type(4))) float;
using s16x8 = __attribute__((ext_vector_type(8))) short;
using u32x4 = __attribute__((ext_vector_type(4))) unsigned int;

__device__ __forceinline__ unsigned short f2bf(float f) {
    unsigned u = __float_as_uint(f);
    u += 0x7fffu + ((u >> 16) & 1u);   // round-to-nearest-even
    return (unsigned short)(u >> 16);
}

// ---------------- CSR build (dst-sorted edge list) ----------------
__global__ void hist_kernel(const int* __restrict__ dst, int* __restrict__ deg, int e) {
    int i = blockIdx.x * blockDim.x + threadIdx.x;
    if (i < e) atomicAdd(&deg[dst[i]], 1);
}

// single block, 1024 threads: each thread scans a contiguous chunk; wave-scan of chunk sums
__global__ void scan_excl(const int* __restrict__ deg, int* __restrict__ rowstart, int n) {
    __shared__ int wsum[16];
    int tid = threadIdx.x;
    int per = (n + 1023) >> 10;
    int b0 = tid * per;
    int s = 0;
    for (int j = 0; j < per; ++j) {
        int i = b0 + j;
        if (i < n) s += deg[i];
    }
    int lane = tid & 63, w = tid >> 6;
    int v = s;
    #pragma unroll
    for (int off = 1; off < 64; off <<= 1) {
        int t = __shfl_up(v, off, 64);
        if (lane >= off) v += t;
    }
    if (lane == 63) wsum[w] = v;
    __syncthreads();
    if (w == 0) {
        int t = (lane < 16) ? wsum[lane] : 0;
        #pragma unroll
        for (int off = 1; off < 16; off <<= 1) {
            int u = __shfl_up(t, off, 64);
            if (lane >= off) t += u;
        }
        if (lane < 16) wsum[lane] = t;
    }
    __syncthreads();
    int base = (w > 0 ? wsum[w - 1] : 0) + v - s;   // exclusive prefix of this chunk
    for (int j = 0; j < per; ++j) {
        int i = b0 + j;
        if (i < n) { rowstart[i] = base; base += deg[i]; }
    }
    if (tid == 0) rowstart[n] = wsum[15];
}

// scatter edges into dst-sorted order, pre-permuting src and edge_attr (kills one
// dependent-load level in the attention gather chain and makes those reads coalesced)
__global__ void scatter_kernel(const int* __restrict__ src, const int* __restrict__ dst,
                               const float* __restrict__ ea,
                               const int* __restrict__ rowstart, int* __restrict__ cursor,
                               int* __restrict__ srcp, float* __restrict__ eap, int e) {
    int i = blockIdx.x * blockDim.x + threadIdx.x;
    if (i < e) {
        int d = dst[i];
        int pos = atomicAdd(&cursor[d], 1);
        int p = rowstart[d] + pos;
        srcp[p] = src[i];
        eap[p] = ea[i];
    }
}

// ---------------- pack weights: Wt[c][K] = bf16(W[k][c&255]), via LDS transpose ----------------
__global__ __launch_bounds__(256) void pack_w(const float* __restrict__ Wq, const float* __restrict__ Wk,
                                              const float* __restrict__ Wv, const float* __restrict__ Ws,
                                              const float* __restrict__ bq, const float* __restrict__ bk,
                                              const float* __restrict__ bv, const float* __restrict__ bs,
                                              unsigned short* __restrict__ Wt, float* __restrict__ bcat,
                                              int K) {
    __shared__ unsigned short t[64][65];
    int k0 = blockIdx.x * 64, c0 = blockIdx.y * 64;
    const float* W = (c0 < 256) ? Wq : (c0 < 512) ? Wk : (c0 < 768) ? Wv : Ws;
    int cc = c0 & 255;
    int tr = threadIdx.x >> 6;    // 0..3
    int tc = threadIdx.x & 63;
    #pragma unroll
    for (int r = tr; r < 64; r += 4)
        t[r][tc] = f2bf(W[(size_t)(k0 + r) * 256 + cc + tc]);
    __syncthreads();
    #pragma unroll
    for (int r = tr; r < 64; r += 4)
        Wt[(size_t)(c0 + r) * K + k0 + tc] = t[tc][r];
    if (blockIdx.x == 0 && threadIdx.x < 64) {
        int c = c0 + threadIdx.x;
        const float* b = (c < 256) ? bq : (c < 512) ? bk : (c < 768) ? bv : bs;
        bcat[c] = b[c & 255];
    }
}

__global__ void to_bf16(const float* __restrict__ in, unsigned short* __restrict__ out, int n4) {
    int i = blockIdx.x * blockDim.x + threadIdx.x;
    if (i < n4) {
        float4 v = ((const float4*)in)[i];
        ushort4 o;
        o.x = f2bf(v.x); o.y = f2bf(v.y); o.z = f2bf(v.z); o.w = f2bf(v.w);
        ((ushort4*)out)[i] = o;
    }
}

// ---------------- bf16 MFMA GEMM: [Q|K|V|S] = A[M][K] x Bt[1024][K]^T + bias ----------------
// 128x128 tile, BK=64, 4 waves (2x2), each wave 64x64 = 4x4 fragments of 16x16x32
// Output panels: col 0-255 -> Qf fp32 [M][256]; 256-511 -> KVb.K bf16; 512-767 -> KVb.V bf16
// (KVb [M][512], K then V — 1 KB/node gather granule); 768-1023 -> Sf fp32 [M][256]
__global__ __launch_bounds__(256) void gemm_mfma(const unsigned short* __restrict__ A,
                                                 const unsigned short* __restrict__ Bt,
                                                 const float* __restrict__ bias,
                                                 float* __restrict__ Qf,
                                                 unsigned short* __restrict__ KVb,
                                                 float* __restrict__ Sf,
                                                 int M, int K) {
    __shared__ unsigned short As[128][72];
    __shared__ unsigned short Bs[128][72];
    const int tid = threadIdx.x;
    const int lane = tid & 63;
    const int wave = tid >> 6;
    const int wr = (wave >> 1) * 64;
    const int wc = (wave & 1) * 64;
    const int g = lane >> 4;
    const int r16 = lane & 15;
    const int rowBase = blockIdx.x * 128;
    const int colBase = blockIdx.y * 128;

    const int srow = tid >> 1;
    const int skh = (tid & 1) * 32;

    f32x4 acc[4][4];
    #pragma unroll
    for (int i = 0; i < 4; ++i)
        #pragma unroll
        for (int j = 0; j < 4; ++j)
            acc[i][j] = (f32x4){0.f, 0.f, 0.f, 0.f};

    for (int k0 = 0; k0 < K; k0 += 64) {
        {
            int grow = rowBase + srow;
            bool ok = grow < M;
            const unsigned short* pa = &A[(size_t)(ok ? grow : 0) * K + k0 + skh];
            #pragma unroll
            for (int i = 0; i < 4; ++i) {
                u32x4 v = ok ? *(const u32x4*)(pa + i * 8) : (u32x4){0u, 0u, 0u, 0u};
                *(u32x4*)&As[srow][skh + i * 8] = v;
            }
            const unsigned short* pb = &Bt[(size_t)(colBase + srow) * K + k0 + skh];
            #pragma unroll
            for (int i = 0; i < 4; ++i)
                *(u32x4*)&Bs[srow][skh + i * 8] = *(const u32x4*)(pb + i * 8);
        }
        __syncthreads();
        #pragma unroll
        for (int kk = 0; kk < 64; kk += 32) {
            s16x8 af[4], bf[4];
            #pragma unroll
            for (int i = 0; i < 4; ++i) af[i] = *(const s16x8*)&As[wr + i * 16 + r16][kk + g * 8];
            #pragma unroll
            for (int j = 0; j < 4; ++j) bf[j] = *(const s16x8*)&Bs[wc + j * 16 + r16][kk + g * 8];
            #pragma unroll
            for (int i = 0; i < 4; ++i)
                #pragma unroll
                for (int j = 0; j < 4; ++j)
                    acc[i][j] = __builtin_amdgcn_mfma_f32_16x16x32_bf16(af[i], bf[j], acc[i][j], 0, 0, 0);
        }
        __syncthreads();
    }

    #pragma unroll
    for (int j = 0; j < 4; ++j) {
        int gcol = colBase + wc + j * 16 + r16;
        int panel = gcol >> 8;
        int pc = gcol & 255;
        float bb = bias[gcol];
        #pragma unroll
        for (int i = 0; i < 4; ++i) {
            #pragma unroll
            for (int r = 0; r < 4; ++r) {
                int grow = rowBase + wr + i * 16 + g * 4 + r;
                if (grow < M) {
                    float val = acc[i][j][r] + bb;
                    if (panel == 0)      Qf[(size_t)grow * 256 + pc] = val;
                    else if (panel == 1) KVb[(size_t)grow * 512 + pc] = f2bf(val);
                    else if (panel == 2) KVb[(size_t)grow * 512 + 256 + pc] = f2bf(val);
                    else                 Sf[(size_t)grow * 256 + pc] = val;
                }
            }
        }
    }
}

// ---------------- attention: one wave per dst node, single-pass online softmax ----------------
// lanes[5]=edge slot (2), [4]=head, [3:0]=8-channel group; 2 edges batched per slot per iter
__global__ __launch_bounds__(256) void attn_kernel(const float* __restrict__ Qf,
                                                   const unsigned short* __restrict__ KVb,
                                                   const float* __restrict__ Sf,
                                                   const int* __restrict__ srcp,
                                                   const float* __restrict__ eap,
                                                   const float* __restrict__ We,
                                                   const int* __restrict__ rowstart,
                                                   float* __restrict__ out, int n) {
    int wave = threadIdx.x >> 6, lane = threadIdx.x & 63;
    int node = blockIdx.x * 4 + wave;
    if (node >= n) return;
    int epar = lane >> 5;
    int h = (lane >> 4) & 1;
    int hc = h * 128 + (lane & 15) * 8;

    float4 qa = *(const float4*)&Qf[(size_t)node * 256 + hc];
    float4 qb = *(const float4*)&Qf[(size_t)node * 256 + hc + 4];
    float4 wea = *(const float4*)&We[hc];
    float4 web = *(const float4*)&We[hc + 4];
    float q[8]  = {qa.x, qa.y, qa.z, qa.w, qb.x, qb.y, qb.z, qb.w};
    float wv[8] = {wea.x, wea.y, wea.z, wea.w, web.x, web.y, web.z, web.w};

    int beg = rowstart[node], end = rowstart[node + 1];
    const float scale = 0.08838834764831845f;   // 1/sqrt(128)
    const unsigned short* KV = KVb + hc;

    float m = -INFINITY, ssum = 0.f;
    float acc[8] = {0.f, 0.f, 0.f, 0.f, 0.f, 0.f, 0.f, 0.f};

    auto process = [&](u32x4 kk, u32x4 vv, float a, bool valid) {
        float kf[8], vf[8], ef[8];
        #pragma unroll
        for (int t = 0; t < 4; ++t) {
            kf[2 * t]     = __uint_as_float(kk[t] << 16);
            kf[2 * t + 1] = __uint_as_float(kk[t] & 0xffff0000u);
            vf[2 * t]     = __uint_as_float(vv[t] << 16);
            vf[2 * t + 1] = __uint_as_float(vv[t] & 0xffff0000u);
        }
        float p = 0.f;
        #pragma unroll
        for (int t = 0; t < 8; ++t) { ef[t] = a * wv[t]; p += q[t] * (kf[t] + ef[t]); }
        p += __shfl_xor(p, 1, 64);
        p += __shfl_xor(p, 2, 64);
        p += __shfl_xor(p, 4, 64);
        p += __shfl_xor(p, 8, 64);
        float alpha = valid ? p * scale : -INFINITY;
        float mnew = fmaxf(m, alpha);
        float corr = __expf(fminf(m - mnew, 0.f));   // 1 when both -inf (nan->0)
        float wgt = valid ? __expf(alpha - mnew) : 0.f;
        ssum = ssum * corr + wgt;
        #pragma unroll
        for (int t = 0; t < 8; ++t) acc[t] = acc[t] * corr + wgt * (vf[t] + ef[t]);
        m = mnew;
    };

    for (int i0 = beg; i0 < end; i0 += 4) {
        int ia = i0 + epar, ib = i0 + 2 + epar;
        bool va = ia < end, vb = ib < end;
        int   sa = srcp[va ? ia : beg];
        float aa = eap[va ? ia : beg];
        int   sb = srcp[vb ? ib : beg];
        float ab = eap[vb ? ib : beg];
        u32x4 ka  = *(const u32x4*)(KV + (size_t)sa * 512);
        u32x4 vva = *(const u32x4*)(KV + (size_t)sa * 512 + 256);
        u32x4 kb  = *(const u32x4*)(KV + (size_t)sb * 512);
        u32x4 vvb = *(const u32x4*)(KV + (size_t)sb * 512 + 256);
        process(ka, vva, aa, va);
        process(kb, vvb, ab, vb);
    }

    // merge the two edge-slot partials (lane ^ 32)
    float m2 = __shfl_xor(m, 32, 64);
    float mm = fmaxf(m, m2);
    float cw = __expf(fminf(m - mm, 0.f));
    float sw = ssum * cw;
    sw += __shfl_xor(sw, 32, 64);
    float o[8];
    #pragma unroll
    for (int t = 0; t < 8; ++t) {
        o[t] = acc[t] * cw;
        o[t] += __shfl_xor(o[t], 32, 64);
    }

    if (epar == 0) {
        float inv = 1.0f / (sw + 1e-16f);
        float4 sk0 = *(const float4*)&Sf[(size_t)node * 256 + hc];
        float4 sk1 = *(const float4*)&Sf[(size_t)node * 256 + hc + 4];
        float4 r0, r1;
        r0.x = o[0] * inv + sk0.x; r0.y = o[1] * inv + sk0.y;
        r0.z = o[2] * inv + sk0.z; r0.w = o[3] * inv + sk0.w;
        r1.x = o[4] * inv + sk1.x; r1.y = o[5] * inv + sk1.y;
        r1.z = o[6] * inv + sk1.z; r1.w = o[7] * inv + sk1.w;
        *(float4*)&out[(size_t)node * 256 + hc] = r0;
        *(float4*)&out[(size_t)node * 256 + hc + 4] = r1;
    }
}

// ---------------- BatchNorm ----------------
__global__ void bn_stats(const float* __restrict__ x, float* __restrict__ sums, int n) {
    int c = threadIdx.x;  // 256
    float s = 0.f, s2 = 0.f;
    for (int r = blockIdx.x; r < n; r += gridDim.x) {
        float v = x[(size_t)r * 256 + c];
        s += v; s2 += v * v;
    }
    atomicAdd(&sums[c], s);
    atomicAdd(&sums[256 + c], s2);
}

__global__ void bn_apply_bf16(const float* __restrict__ x, const float* __restrict__ sums,
                              const float* __restrict__ g, const float* __restrict__ b,
                              unsigned short* __restrict__ y, int n) {
    int idx = blockIdx.x * blockDim.x + threadIdx.x;
    if (idx >= n * 256) return;
    int c = idx & 255;
    float invn = 1.0f / (float)n;
    float mu = sums[c] * invn;
    float var = sums[256 + c] * invn - mu * mu;
    float v = (x[idx] - mu) * rsqrtf(var + BN_EPS) * g[c] + b[c];
    y[idx] = f2bf(fmaxf(v, 0.f));
}

__global__ void bn_apply(const float* __restrict__ x, const float* __restrict__ sums,
                         const float* __restrict__ g, const float* __restrict__ b,
                         float* __restrict__ y, int n) {
    int idx = blockIdx.x * blockDim.x + threadIdx.x;
    if (idx >= n * 256) return;
    int c = idx & 255;
    float invn = 1.0f / (float)n;
    float mu = sums[c] * invn;
    float var = sums[256 + c] * invn - mu * mu;
    float v = (x[idx] - mu) * rsqrtf(var + BN_EPS) * g[c] + b[c];
    y[idx] = fmaxf(v, 0.f);
}

extern "C" void kernel_launch(void* const* d_in, const int* in_sizes, int n_in,
                              void* d_out, int out_size, void* d_ws, size_t ws_size,
                              hipStream_t stream) {
    const float* x         = (const float*)d_in[0];
    const int*   edge_idx  = (const int*)d_in[1];
    const float* edge_attr = (const float*)d_in[2];
    const float* Wq1 = (const float*)d_in[3];  const float* bq1 = (const float*)d_in[4];
    const float* Wk1 = (const float*)d_in[5];  const float* bk1 = (const float*)d_in[6];
    const float* Wv1 = (const float*)d_in[7];  const float* bv1 = (const float*)d_in[8];
    const float* We1 = (const float*)d_in[9];
    const float* Ws1 = (const float*)d_in[10]; const float* bs1 = (const float*)d_in[11];
    const float* g1  = (const float*)d_in[12]; const float* b1  = (const float*)d_in[13];
    const float* Wq2 = (const float*)d_in[14]; const float* bq2 = (const float*)d_in[15];
    const float* Wk2 = (const float*)d_in[16]; const float* bk2 = (const float*)d_in[17];
    const float* Wv2 = (const float*)d_in[18]; const float* bv2 = (const float*)d_in[19];
    const float* We2 = (const float*)d_in[20];
    const float* Ws2 = (const float*)d_in[21]; const float* bs2 = (const float*)d_in[22];
    const float* g2  = (const float*)d_in[23]; const float* b2  = (const float*)d_in[24];

    const int N = in_sizes[0] / 128;   // 10000
    const int E = in_sizes[1] / 2;     // 160000
    const int* src = edge_idx;
    const int* dst = edge_idx + E;

    char* ws = (char*)d_ws;
    size_t off = 0;
    auto alloc = [&](size_t bytes) -> void* {
        void* p = ws + off;
        off += (bytes + 255) & ~(size_t)255;
        return p;
    };
    float*          Qf       = (float*)alloc((size_t)N * 256 * 4);
    unsigned short* KVb      = (unsigned short*)alloc((size_t)N * 512 * 2);
    float*          Sf       = (float*)alloc((size_t)N * 256 * 4);
    float*          attn_out = (float*)alloc((size_t)N * 256 * 4);
    unsigned short* h1b      = (unsigned short*)alloc((size_t)N * 256 * 2);
    unsigned short* xb       = (unsigned short*)alloc((size_t)N * 128 * 2);
    unsigned short* Wt       = (unsigned short*)alloc((size_t)1024 * 256 * 2);
    float*          bcat     = (float*)alloc(1024 * 4);
    int*            deg      = (int*)alloc((size_t)N * 4);
    int*            rowstart = (int*)alloc((size_t)(N + 1) * 4);
    int*            cursor   = (int*)alloc((size_t)N * 4);
    int*            srcp     = (int*)alloc((size_t)E * 4);
    float*          eap      = (float*)alloc((size_t)E * 4);
    float*          bn_sums  = (float*)alloc(512 * 4);

    // ---- CSR build (shared by both layers) ----
    hipMemsetAsync(deg, 0, (size_t)N * 4, stream);
    hipMemsetAsync(cursor, 0, (size_t)N * 4, stream);
    hist_kernel<<<(E + 255) / 256, 256, 0, stream>>>(dst, deg, E);
    scan_excl<<<1, 1024, 0, stream>>>(deg, rowstart, N);
    scatter_kernel<<<(E + 255) / 256, 256, 0, stream>>>(src, dst, edge_attr, rowstart, cursor,
                                                        srcp, eap, E);

    dim3 gemm_grid((N + 127) / 128, 8);
    int attn_blocks = (N + 3) / 4;

    // ---- layer 1 (K = 128) ----
    to_bf16<<<((N * 128 / 4) + 255) / 256, 256, 0, stream>>>(x, xb, N * 128 / 4);
    pack_w<<<dim3(2, 16), 256, 0, stream>>>(Wq1, Wk1, Wv1, Ws1, bq1, bk1, bv1, bs1, Wt, bcat, 128);
    gemm_mfma<<<gemm_grid, 256, 0, stream>>>(xb, Wt, bcat, Qf, KVb, Sf, N, 128);
    attn_kernel<<<attn_blocks, 256, 0, stream>>>(Qf, KVb, Sf, srcp, eap, We1, rowstart,
                                                 attn_out, N);
    hipMemsetAsync(bn_sums, 0, 512 * 4, stream);
    bn_stats<<<256, 256, 0, stream>>>(attn_out, bn_sums, N);
    bn_apply_bf16<<<(N * 256 + 255) / 256, 256, 0, stream>>>(attn_out, bn_sums, g1, b1, h1b, N);

    // ---- layer 2 (K = 256) ----
    pack_w<<<dim3(4, 16), 256, 0, stream>>>(Wq2, Wk2, Wv2, Ws2, bq2, bk2, bv2, bs2, Wt, bcat, 256);
    gemm_mfma<<<gemm_grid, 256, 0, stream>>>(h1b, Wt, bcat, Qf, KVb, Sf, N, 256);
    attn_kernel<<<attn_blocks, 256, 0, stream>>>(Qf, KVb, Sf, srcp, eap, We2, rowstart,
                                                 attn_out, N);
    hipMemsetAsync(bn_sums, 0, 512 * 4, stream);
    bn_stats<<<256, 256, 0, stream>>>(attn_out, bn_sums, N);
    bn_apply<<<(N * 256 + 255) / 256, 256, 0, stream>>>(attn_out, bn_sums, g2, b2, (float*)d_out, N);
}

// Round 4
// 191.493 us; speedup vs baseline: 2.0066x; 1.0873x over previous
//
#include <hip/hip_runtime.h>

#define BN_EPS 1e-5f

using f32x4 = __attribute__((ext_vector_type(4))) float;
using s16x8 = __attribute__((ext_vector_type(8))) short;
using u32x4 = __attribute__((ext_vector_type(4))) unsigned int;

__device__ __forceinline__ unsigned short f2bf(float f) {
    unsigned u = __float_as_uint(f);
    u += 0x7fffu + ((u >> 16) & 1u);   // round-to-nearest-even
    return (unsigned short)(u >> 16);
}

// ---------------- CSR build ----------------
__global__ void hist_kernel(const int* __restrict__ dst, int* __restrict__ deg, int e) {
    int i = blockIdx.x * blockDim.x + threadIdx.x;
    if (i < e) atomicAdd(&deg[dst[i]], 1);
}

__global__ void scan_excl(const int* __restrict__ deg, int* __restrict__ rowstart, int n) {
    __shared__ int wsum[16];
    int tid = threadIdx.x;
    int per = (n + 1023) >> 10;
    int b0 = tid * per;
    int s = 0;
    for (int j = 0; j < per; ++j) {
        int i = b0 + j;
        if (i < n) s += deg[i];
    }
    int lane = tid & 63, w = tid >> 6;
    int v = s;
    #pragma unroll
    for (int off = 1; off < 64; off <<= 1) {
        int t = __shfl_up(v, off, 64);
        if (lane >= off) v += t;
    }
    if (lane == 63) wsum[w] = v;
    __syncthreads();
    if (w == 0) {
        int t = (lane < 16) ? wsum[lane] : 0;
        #pragma unroll
        for (int off = 1; off < 16; off <<= 1) {
            int u = __shfl_up(t, off, 64);
            if (lane >= off) t += u;
        }
        if (lane < 16) wsum[lane] = t;
    }
    __syncthreads();
    int base = (w > 0 ? wsum[w - 1] : 0) + v - s;
    for (int j = 0; j < per; ++j) {
        int i = b0 + j;
        if (i < n) { rowstart[i] = base; base += deg[i]; }
    }
    if (tid == 0) rowstart[n] = wsum[15];
}

// scatter edges dst-sorted; pack (src, edge_attr) into one int2 per edge
__global__ void scatter_kernel(const int* __restrict__ src, const int* __restrict__ dst,
                               const float* __restrict__ ea,
                               const int* __restrict__ rowstart, int* __restrict__ cursor,
                               int2* __restrict__ sae, int e) {
    int i = blockIdx.x * blockDim.x + threadIdx.x;
    if (i < e) {
        int d = dst[i];
        int pos = atomicAdd(&cursor[d], 1);
        sae[rowstart[d] + pos] = make_int2(src[i], __float_as_int(ea[i]));
    }
}

// ---------------- prep: weight transposes + x->bf16 + bias concat + zero-init ----------------
// blocks [0,32): pack W1 (K=128); [32,96): pack W2 (K=256); [96,...): to_bf16 + zeros + bcat
__global__ __launch_bounds__(256) void prep_kernel(
    const float* __restrict__ x,
    const float* __restrict__ Wq1, const float* __restrict__ Wk1,
    const float* __restrict__ Wv1, const float* __restrict__ Ws1,
    const float* __restrict__ bq1, const float* __restrict__ bk1,
    const float* __restrict__ bv1, const float* __restrict__ bs1,
    const float* __restrict__ Wq2, const float* __restrict__ Wk2,
    const float* __restrict__ Wv2, const float* __restrict__ Ws2,
    const float* __restrict__ bq2, const float* __restrict__ bk2,
    const float* __restrict__ bv2, const float* __restrict__ bs2,
    unsigned short* __restrict__ xb, unsigned short* __restrict__ Wt1,
    unsigned short* __restrict__ Wt2, float* __restrict__ bcat1, float* __restrict__ bcat2,
    int* __restrict__ deg, int* __restrict__ cursor,
    float* __restrict__ bns1, float* __restrict__ bns2, int N, int n4) {
    __shared__ unsigned short t[64][65];
    int bid = blockIdx.x;
    if (bid < 96) {
        int K, b;
        const float *Wq, *Wk, *Wv, *Ws;
        unsigned short* Wt;
        if (bid < 32) { K = 128; b = bid; Wq = Wq1; Wk = Wk1; Wv = Wv1; Ws = Ws1; Wt = Wt1; }
        else          { K = 256; b = bid - 32; Wq = Wq2; Wk = Wk2; Wv = Wv2; Ws = Ws2; Wt = Wt2; }
        int k0 = (b >> 4) * 64, c0 = (b & 15) * 64;
        const float* W = (c0 < 256) ? Wq : (c0 < 512) ? Wk : (c0 < 768) ? Wv : Ws;
        int cc = c0 & 255;
        int tr = threadIdx.x >> 6;
        int tc = threadIdx.x & 63;
        #pragma unroll
        for (int r = tr; r < 64; r += 4)
            t[r][tc] = f2bf(W[(size_t)(k0 + r) * 256 + cc + tc]);
        __syncthreads();
        #pragma unroll
        for (int r = tr; r < 64; r += 4)
            Wt[(size_t)(c0 + r) * K + k0 + tc] = t[tc][r];
    } else {
        int idx = (bid - 96) * 256 + threadIdx.x;
        if (idx < n4) {
            float4 v = ((const float4*)x)[idx];
            ushort4 o;
            o.x = f2bf(v.x); o.y = f2bf(v.y); o.z = f2bf(v.z); o.w = f2bf(v.w);
            ((ushort4*)xb)[idx] = o;
        }
        if (idx < N) { deg[idx] = 0; cursor[idx] = 0; }
        if (idx < 512) { bns1[idx] = 0.f; bns2[idx] = 0.f; }
        if (idx < 1024) {
            const float* b1 = (idx < 256) ? bq1 : (idx < 512) ? bk1 : (idx < 768) ? bv1 : bs1;
            const float* b2 = (idx < 256) ? bq2 : (idx < 512) ? bk2 : (idx < 768) ? bv2 : bs2;
            bcat1[idx] = b1[idx & 255];
            bcat2[idx] = b2[idx & 255];
        }
    }
}

// ---------------- bf16 MFMA GEMM: [Q|K|V|S] = A[M][K] x Bt[1024][K]^T + bias ----------------
// FUSED_BN: A is fp32 [M][256] pre-BN; apply (x*scale+shift), relu, bf16 in A-staging.
__global__ __launch_bounds__(256) void gemm_core(const unsigned short* __restrict__ Ab,
                                                 const float* __restrict__ Af,
                                                 const unsigned short* __restrict__ Bt,
                                                 const float* __restrict__ bias,
                                                 const float* __restrict__ bns,
                                                 const float* __restrict__ bng,
                                                 const float* __restrict__ bnb,
                                                 float invn, int FUSED_BN,
                                                 float* __restrict__ Qf,
                                                 unsigned short* __restrict__ KVb,
                                                 float* __restrict__ Sf,
                                                 int M, int K) {
    __shared__ unsigned short As[128][72];
    __shared__ unsigned short Bs[128][72];
    __shared__ float bnsc[256], bnsh[256];
    const int tid = threadIdx.x;
    const int lane = tid & 63;
    const int wave = tid >> 6;
    const int wr = (wave >> 1) * 64;
    const int wc = (wave & 1) * 64;
    const int g = lane >> 4;
    const int r16 = lane & 15;
    const int rowBase = blockIdx.x * 128;
    const int colBase = blockIdx.y * 128;
    const int srow = tid >> 1;
    const int skh = (tid & 1) * 32;

    if (FUSED_BN) {
        int c = tid;
        float s = bns[c], s2 = bns[256 + c];
        float mu = s * invn;
        float var = s2 * invn - mu * mu;
        float sc = rsqrtf(var + BN_EPS) * bng[c];
        bnsc[c] = sc;
        bnsh[c] = bnb[c] - mu * sc;
        __syncthreads();
    }

    f32x4 acc[4][4];
    #pragma unroll
    for (int i = 0; i < 4; ++i)
        #pragma unroll
        for (int j = 0; j < 4; ++j)
            acc[i][j] = (f32x4){0.f, 0.f, 0.f, 0.f};

    for (int k0 = 0; k0 < K; k0 += 64) {
        {
            int grow = rowBase + srow;
            bool ok = grow < M;
            if (FUSED_BN) {
                if (ok) {
                    const float* pa = &Af[(size_t)grow * K + k0 + skh];
                    #pragma unroll
                    for (int i = 0; i < 4; ++i) {
                        int kk = k0 + skh + i * 8;
                        f32x4 lo = *(const f32x4*)(pa + i * 8);
                        f32x4 hi = *(const f32x4*)(pa + i * 8 + 4);
                        u32x4 wrd;
                        #pragma unroll
                        for (int e = 0; e < 2; ++e) {
                            unsigned a0 = f2bf(fmaxf(lo[2*e]   * bnsc[kk+2*e]   + bnsh[kk+2*e],   0.f));
                            unsigned a1 = f2bf(fmaxf(lo[2*e+1] * bnsc[kk+2*e+1] + bnsh[kk+2*e+1], 0.f));
                            unsigned a2 = f2bf(fmaxf(hi[2*e]   * bnsc[kk+4+2*e]   + bnsh[kk+4+2*e],   0.f));
                            unsigned a3 = f2bf(fmaxf(hi[2*e+1] * bnsc[kk+4+2*e+1] + bnsh[kk+4+2*e+1], 0.f));
                            wrd[e] = a0 | (a1 << 16);
                            wrd[2 + e] = a2 | (a3 << 16);
                        }
                        *(u32x4*)&As[srow][skh + i * 8] = wrd;
                    }
                } else {
                    #pragma unroll
                    for (int i = 0; i < 4; ++i)
                        *(u32x4*)&As[srow][skh + i * 8] = (u32x4){0u, 0u, 0u, 0u};
                }
            } else {
                const unsigned short* pa = &Ab[(size_t)(ok ? grow : 0) * K + k0 + skh];
                #pragma unroll
                for (int i = 0; i < 4; ++i) {
                    u32x4 v = ok ? *(const u32x4*)(pa + i * 8) : (u32x4){0u, 0u, 0u, 0u};
                    *(u32x4*)&As[srow][skh + i * 8] = v;
                }
            }
            const unsigned short* pb = &Bt[(size_t)(colBase + srow) * K + k0 + skh];
            #pragma unroll
            for (int i = 0; i < 4; ++i)
                *(u32x4*)&Bs[srow][skh + i * 8] = *(const u32x4*)(pb + i * 8);
        }
        __syncthreads();
        #pragma unroll
        for (int kk = 0; kk < 64; kk += 32) {
            s16x8 af[4], bf[4];
            #pragma unroll
            for (int i = 0; i < 4; ++i) af[i] = *(const s16x8*)&As[wr + i * 16 + r16][kk + g * 8];
            #pragma unroll
            for (int j = 0; j < 4; ++j) bf[j] = *(const s16x8*)&Bs[wc + j * 16 + r16][kk + g * 8];
            #pragma unroll
            for (int i = 0; i < 4; ++i)
                #pragma unroll
                for (int j = 0; j < 4; ++j)
                    acc[i][j] = __builtin_amdgcn_mfma_f32_16x16x32_bf16(af[i], bf[j], acc[i][j], 0, 0, 0);
        }
        __syncthreads();
    }

    #pragma unroll
    for (int j = 0; j < 4; ++j) {
        int gcol = colBase + wc + j * 16 + r16;
        int panel = gcol >> 8;
        int pc = gcol & 255;
        float bb = bias[gcol];
        #pragma unroll
        for (int i = 0; i < 4; ++i) {
            #pragma unroll
            for (int r = 0; r < 4; ++r) {
                int grow = rowBase + wr + i * 16 + g * 4 + r;
                if (grow < M) {
                    float val = acc[i][j][r] + bb;
                    if (panel == 0)      Qf[(size_t)grow * 256 + pc] = val;
                    else if (panel == 1) KVb[(size_t)grow * 512 + pc] = f2bf(val);
                    else if (panel == 2) KVb[(size_t)grow * 512 + 256 + pc] = f2bf(val);
                    else                 Sf[(size_t)grow * 256 + pc] = val;
                }
            }
        }
    }
}

// ---------------- attention: one wave per dst node, online softmax, 8 edges in flight ----------------
// lanes[5]=edge slot (2), [4]=head, [3:0]=8-channel group; 4 edges batched per slot per iter
__global__ __launch_bounds__(256) void attn_kernel(const float* __restrict__ Qf,
                                                   const unsigned short* __restrict__ KVb,
                                                   const float* __restrict__ Sf,
                                                   const int2* __restrict__ sae,
                                                   const float* __restrict__ We,
                                                   const int* __restrict__ rowstart,
                                                   float* __restrict__ out, int n) {
    int wave = threadIdx.x >> 6, lane = threadIdx.x & 63;
    int node = blockIdx.x * 4 + wave;
    if (node >= n) return;
    int epar = lane >> 5;
    int hc = ((lane >> 4) & 1) * 128 + (lane & 15) * 8;

    float4 qa = *(const float4*)&Qf[(size_t)node * 256 + hc];
    float4 qb = *(const float4*)&Qf[(size_t)node * 256 + hc + 4];
    float4 wea = *(const float4*)&We[hc];
    float4 web = *(const float4*)&We[hc + 4];
    float q[8]  = {qa.x, qa.y, qa.z, qa.w, qb.x, qb.y, qb.z, qb.w};
    float wv[8] = {wea.x, wea.y, wea.z, wea.w, web.x, web.y, web.z, web.w};

    const float scale = 0.08838834764831845f;   // 1/sqrt(128)
    float qwe = 0.f;
    #pragma unroll
    for (int t = 0; t < 8; ++t) qwe += q[t] * wv[t];
    qwe += __shfl_xor(qwe, 1, 64);
    qwe += __shfl_xor(qwe, 2, 64);
    qwe += __shfl_xor(qwe, 4, 64);
    qwe += __shfl_xor(qwe, 8, 64);
    float qwes = qwe * scale;

    int beg = rowstart[node], end = rowstart[node + 1];
    const unsigned short* KV = KVb + hc;

    float m = -INFINITY, ssum = 0.f, wa = 0.f;
    float acc[8] = {0.f, 0.f, 0.f, 0.f, 0.f, 0.f, 0.f, 0.f};

    for (int i0 = beg; i0 < end; i0 += 8) {
        float aval[4];
        bool val[4];
        u32x4 kw[4], vw[4];
        #pragma unroll
        for (int j = 0; j < 4; ++j) {
            int i = i0 + 2 * j + epar;
            val[j] = i < end;
            int2 se = sae[val[j] ? i : beg];
            aval[j] = __int_as_float(se.y);
            const unsigned short* kp = KV + (size_t)se.x * 512;
            kw[j] = *(const u32x4*)kp;
            vw[j] = *(const u32x4*)(kp + 256);
        }
        float p[4];
        #pragma unroll
        for (int j = 0; j < 4; ++j) {
            float s = 0.f;
            #pragma unroll
            for (int t = 0; t < 4; ++t) {
                s += q[2 * t]     * __uint_as_float(kw[j][t] << 16);
                s += q[2 * t + 1] * __uint_as_float(kw[j][t] & 0xffff0000u);
            }
            s += __shfl_xor(s, 1, 64);
            s += __shfl_xor(s, 2, 64);
            s += __shfl_xor(s, 4, 64);
            s += __shfl_xor(s, 8, 64);
            p[j] = s;
        }
        #pragma unroll
        for (int j = 0; j < 4; ++j) {
            float alpha = val[j] ? p[j] * scale + aval[j] * qwes : -INFINITY;
            float mnew = fmaxf(m, alpha);
            float corr = __expf(fminf(m - mnew, 0.f));   // 1 when both -inf (nan->0)
            float w = val[j] ? __expf(alpha - mnew) : 0.f;
            ssum = ssum * corr + w;
            wa = wa * corr + w * aval[j];
            #pragma unroll
            for (int t = 0; t < 4; ++t) {
                acc[2 * t]     = acc[2 * t]     * corr + w * __uint_as_float(vw[j][t] << 16);
                acc[2 * t + 1] = acc[2 * t + 1] * corr + w * __uint_as_float(vw[j][t] & 0xffff0000u);
            }
            m = mnew;
        }
    }

    // merge the two edge-slot partials (lane ^ 32)
    float m2 = __shfl_xor(m, 32, 64);
    float mm = fmaxf(m, m2);
    float cw = __expf(fminf(m - mm, 0.f));
    float sw = ssum * cw;
    sw += __shfl_xor(sw, 32, 64);
    float waw = wa * cw;
    waw += __shfl_xor(waw, 32, 64);
    float o[8];
    #pragma unroll
    for (int t = 0; t < 8; ++t) {
        o[t] = acc[t] * cw;
        o[t] += __shfl_xor(o[t], 32, 64);
    }

    if (epar == 0) {
        float inv = 1.0f / (sw + 1e-16f);
        float4 sk0 = *(const float4*)&Sf[(size_t)node * 256 + hc];
        float4 sk1 = *(const float4*)&Sf[(size_t)node * 256 + hc + 4];
        float4 r0, r1;
        r0.x = (o[0] + waw * wv[0]) * inv + sk0.x;
        r0.y = (o[1] + waw * wv[1]) * inv + sk0.y;
        r0.z = (o[2] + waw * wv[2]) * inv + sk0.z;
        r0.w = (o[3] + waw * wv[3]) * inv + sk0.w;
        r1.x = (o[4] + waw * wv[4]) * inv + sk1.x;
        r1.y = (o[5] + waw * wv[5]) * inv + sk1.y;
        r1.z = (o[6] + waw * wv[6]) * inv + sk1.z;
        r1.w = (o[7] + waw * wv[7]) * inv + sk1.w;
        *(float4*)&out[(size_t)node * 256 + hc] = r0;
        *(float4*)&out[(size_t)node * 256 + hc + 4] = r1;
    }
}

// ---------------- BatchNorm ----------------
__global__ void bn_stats(const float* __restrict__ x, float* __restrict__ sums, int n) {
    int c = threadIdx.x;  // 256
    float s = 0.f, s2 = 0.f;
    for (int r = blockIdx.x; r < n; r += gridDim.x) {
        float v = x[(size_t)r * 256 + c];
        s += v; s2 += v * v;
    }
    atomicAdd(&sums[c], s);
    atomicAdd(&sums[256 + c], s2);
}

__global__ void bn_apply(const float* __restrict__ x, const float* __restrict__ sums,
                         const float* __restrict__ g, const float* __restrict__ b,
                         float* __restrict__ y, int n) {
    int idx = blockIdx.x * blockDim.x + threadIdx.x;
    if (idx >= n * 256) return;
    int c = idx & 255;
    float invn = 1.0f / (float)n;
    float mu = sums[c] * invn;
    float var = sums[256 + c] * invn - mu * mu;
    float v = (x[idx] - mu) * rsqrtf(var + BN_EPS) * g[c] + b[c];
    y[idx] = fmaxf(v, 0.f);
}

extern "C" void kernel_launch(void* const* d_in, const int* in_sizes, int n_in,
                              void* d_out, int out_size, void* d_ws, size_t ws_size,
                              hipStream_t stream) {
    const float* x         = (const float*)d_in[0];
    const int*   edge_idx  = (const int*)d_in[1];
    const float* edge_attr = (const float*)d_in[2];
    const float* Wq1 = (const float*)d_in[3];  const float* bq1 = (const float*)d_in[4];
    const float* Wk1 = (const float*)d_in[5];  const float* bk1 = (const float*)d_in[6];
    const float* Wv1 = (const float*)d_in[7];  const float* bv1 = (const float*)d_in[8];
    const float* We1 = (const float*)d_in[9];
    const float* Ws1 = (const float*)d_in[10]; const float* bs1 = (const float*)d_in[11];
    const float* g1  = (const float*)d_in[12]; const float* b1  = (const float*)d_in[13];
    const float* Wq2 = (const float*)d_in[14]; const float* bq2 = (const float*)d_in[15];
    const float* Wk2 = (const float*)d_in[16]; const float* bk2 = (const float*)d_in[17];
    const float* Wv2 = (const float*)d_in[18]; const float* bv2 = (const float*)d_in[19];
    const float* We2 = (const float*)d_in[20];
    const float* Ws2 = (const float*)d_in[21]; const float* bs2 = (const float*)d_in[22];
    const float* g2  = (const float*)d_in[23]; const float* b2  = (const float*)d_in[24];

    const int N = in_sizes[0] / 128;   // 10000
    const int E = in_sizes[1] / 2;     // 160000
    const int* src = edge_idx;
    const int* dst = edge_idx + E;

    char* ws = (char*)d_ws;
    size_t off = 0;
    auto alloc = [&](size_t bytes) -> void* {
        void* p = ws + off;
        off += (bytes + 255) & ~(size_t)255;
        return p;
    };
    float*          Qf       = (float*)alloc((size_t)N * 256 * 4);
    unsigned short* KVb      = (unsigned short*)alloc((size_t)N * 512 * 2);
    float*          Sf       = (float*)alloc((size_t)N * 256 * 4);
    float*          attn_out = (float*)alloc((size_t)N * 256 * 4);
    unsigned short* xb       = (unsigned short*)alloc((size_t)N * 128 * 2);
    unsigned short* Wt1      = (unsigned short*)alloc((size_t)1024 * 128 * 2);
    unsigned short* Wt2      = (unsigned short*)alloc((size_t)1024 * 256 * 2);
    float*          bcat1    = (float*)alloc(1024 * 4);
    float*          bcat2    = (float*)alloc(1024 * 4);
    int*            deg      = (int*)alloc((size_t)N * 4);
    int*            rowstart = (int*)alloc((size_t)(N + 1) * 4);
    int*            cursor   = (int*)alloc((size_t)N * 4);
    int2*           sae      = (int2*)alloc((size_t)E * 8);
    float*          bns1     = (float*)alloc(512 * 4);
    float*          bns2     = (float*)alloc(512 * 4);

    const int n4 = N * 128 / 4;
    const float invn = 1.0f / (float)N;

    // 1: prep (packs, casts, zero-inits — replaces 4 memsets + 4 kernels)
    prep_kernel<<<96 + (n4 + 255) / 256, 256, 0, stream>>>(
        x, Wq1, Wk1, Wv1, Ws1, bq1, bk1, bv1, bs1,
        Wq2, Wk2, Wv2, Ws2, bq2, bk2, bv2, bs2,
        xb, Wt1, Wt2, bcat1, bcat2, deg, cursor, bns1, bns2, N, n4);
    // 2-4: CSR build
    hist_kernel<<<(E + 255) / 256, 256, 0, stream>>>(dst, deg, E);
    scan_excl<<<1, 1024, 0, stream>>>(deg, rowstart, N);
    scatter_kernel<<<(E + 255) / 256, 256, 0, stream>>>(src, dst, edge_attr, rowstart, cursor,
                                                        sae, E);

    dim3 gemm_grid((N + 127) / 128, 8);
    int attn_blocks = (N + 3) / 4;

    // ---- layer 1 (K = 128) ----
    gemm_core<<<gemm_grid, 256, 0, stream>>>(xb, nullptr, Wt1, bcat1,
                                             nullptr, nullptr, nullptr, 0.f, 0,
                                             Qf, KVb, Sf, N, 128);
    attn_kernel<<<attn_blocks, 256, 0, stream>>>(Qf, KVb, Sf, sae, We1, rowstart, attn_out, N);
    bn_stats<<<256, 256, 0, stream>>>(attn_out, bns1, N);

    // ---- layer 2 (K = 256), BN1+ReLU+bf16 fused into A-staging ----
    gemm_core<<<gemm_grid, 256, 0, stream>>>(nullptr, attn_out, Wt2, bcat2,
                                             bns1, g1, b1, invn, 1,
                                             Qf, KVb, Sf, N, 256);
    attn_kernel<<<attn_blocks, 256, 0, stream>>>(Qf, KVb, Sf, sae, We2, rowstart, attn_out, N);
    bn_stats<<<256, 256, 0, stream>>>(attn_out, bns2, N);
    bn_apply<<<(N * 256 + 255) / 256, 256, 0, stream>>>(attn_out, bns2, g2, b2, (float*)d_out, N);
}